// Round 11
// baseline (572.154 us; speedup 1.0000x reference)
//
#include <hip/hip_runtime.h>
#include <hip/hip_bf16.h>
#include <cstdint>
#include <cstddef>

// Problem constants (fixed by reference)
#define DM   1024
#define NH   16
#define DH   64
#define SEQ  2048
#define BB   2
#define NREL 257
#define BHN  (BB*NH)          // 32 (b,h) pairs
#define ROWS (BB*SEQ)         // 4096 (b,s) rows

typedef __attribute__((ext_vector_type(8))) short bf16x8;
typedef __attribute__((ext_vector_type(4))) float f32x4;
typedef __attribute__((ext_vector_type(8))) unsigned short us8;
typedef __attribute__((ext_vector_type(4))) unsigned short us4;

__device__ __forceinline__ unsigned short f2bf(float x){
  union { float f; unsigned u; } v; v.f = x;
  unsigned r = v.u + 0x7fffu + ((v.u >> 16) & 1u);
  return (unsigned short)(r >> 16);
}
__device__ __forceinline__ float b2f(unsigned short h){
  union { unsigned u; float f; } v; v.u = ((unsigned)h) << 16;
  return v.f;
}

__device__ __forceinline__ void gload_lds16(const void* g, void* l){
  __builtin_amdgcn_global_load_lds((const __attribute__((address_space(1))) unsigned int*)g,
                                   (__attribute__((address_space(3))) unsigned int*)l, 16, 0, 0);
}

// ---------------- prep kernels ----------------

// fp32 -> bf16 cast (vectorized), n multiple of 4
__global__ void k_cast(const float* __restrict__ x, unsigned short* __restrict__ o, int n4){
  int i = blockIdx.x*blockDim.x + threadIdx.x;
  int st = gridDim.x*blockDim.x;
  for (; i < n4; i += st){
    float4 f = ((const float4*)x)[i];
    us4 v = { f2bf(f.x), f2bf(f.y), f2bf(f.z), f2bf(f.w) };
    *(us4*)(o + (size_t)i*4) = v;
  }
}

// W[1024][1024] fp32 -> T[1024][1024] bf16 with T[n][k] = W[k][n]
__global__ void k_wtrans(const float* __restrict__ W, unsigned short* __restrict__ T){
  __shared__ float t[64][65];
  int k0 = blockIdx.x*64, n0 = blockIdx.y*64;
  int tid = threadIdx.x;
  for (int u = tid; u < 4096; u += 256){
    int r = u >> 6, c = u & 63;
    t[r][c] = W[(size_t)(k0+r)*DM + n0 + c];
  }
  __syncthreads();
  for (int u = tid; u < 4096; u += 256){
    int r = u >> 6, c = u & 63;   // output row n0+r, col k0+c
    T[(size_t)(n0+r)*DM + k0 + c] = f2bf(t[c][r]);
  }
}

// rel_k_emb [257][64] fp32 -> [272][64] bf16 (zero pad rows 257..271); clamped load
__global__ void k_embk(const float* __restrict__ e, unsigned short* __restrict__ eb){
  int i = blockIdx.x*256 + threadIdx.x;
  if (i >= 272*64) return;
  int r = i >> 6;
  float v = e[min(i, NREL*64 - 1)];
  eb[i] = (r < NREL) ? f2bf(v) : (unsigned short)0;
}

// rel_v_emb -> embT[d][j] = rv[j+1][d] bf16, j in [0,255), col 255 zero-padded
__global__ void k_embt(const float* __restrict__ rv, unsigned short* __restrict__ embT){
  int i = blockIdx.x*256 + threadIdx.x;
  if (i >= 64*256) return;
  int d = i >> 8, j = i & 255;
  float v = rv[(size_t)min(j+1, 256)*DH + d];
  embT[i] = (j < 255) ? f2bf(v) : (unsigned short)0;
}

// ---------------- projection GEMM (plain bf16, head-scatter epilogue) ----------------
__launch_bounds__(256, 2)
__global__ void k_proj(const unsigned short* __restrict__ A, const unsigned short* __restrict__ Bt,
                       const float* __restrict__ bias, unsigned short* __restrict__ O){
  __shared__ __align__(16) unsigned short sm[2*4096];
  const int tid = threadIdx.x;
  const int w = tid >> 6, lane = tid & 63;
  const int m0 = (blockIdx.x >> 3) * 128;
  const int n0 = (blockIdx.x & 7) * 128;
  const int wr = (w >> 1) * 64, wc = (w & 1) * 64;
  const int fr = lane & 15, fo = (lane >> 4)*8, fq = (lane >> 4)*4;
  f32x4 acc[4][4] = {};
  for (int k0 = 0; k0 < DM; k0 += 32){
    const unsigned short* srcs[2] = { A + (size_t)m0*DM + k0, Bt + (size_t)n0*DM + k0 };
#pragma unroll
    for (int t = 0; t < 2; ++t)
#pragma unroll
      for (int p = 0; p < 2; ++p){
        int o = p*4096 + tid*16;
        int row = o >> 6, cb = o & 63;
        const char* g = (const char*)(srcs[t] + (size_t)row*DM) + cb;
        char* l = ((char*)sm) + t*8192 + o;
        gload_lds16(g, l);
      }
    __syncthreads();
    bf16x8 af[4], bf[4];
#pragma unroll
    for (int i = 0; i < 4; ++i){
      af[i] = *(const bf16x8*)&sm[0*4096 + (wr + i*16 + fr)*32 + fo];
      bf[i] = *(const bf16x8*)&sm[1*4096 + (wc + i*16 + fr)*32 + fo];
    }
#pragma unroll
    for (int i = 0; i < 4; ++i)
#pragma unroll
      for (int j = 0; j < 4; ++j)
        acc[i][j] = __builtin_amdgcn_mfma_f32_16x16x32_bf16(af[i], bf[j], acc[i][j], 0,0,0);
    __syncthreads();
  }
#pragma unroll
  for (int i = 0; i < 4; ++i)
#pragma unroll
    for (int j = 0; j < 4; ++j){
      int col = n0 + wc + j*16 + fr;
      float bs = bias[col];
      int h = col >> 6, d = col & 63;
#pragma unroll
      for (int r = 0; r < 4; ++r){
        int row = m0 + wr + i*16 + fq + r;
        int b = row >> 11, s = row & 2047;
        O[((size_t)(b*NH + h)*SEQ + s)*DH + d] = f2bf(acc[i][j][r] + bs);
      }
    }
}

// ---------------- V transpose: vh[bh][s][d] -> vht[bh][d][s] ----------------
__global__ void k_vtrans(const unsigned short* __restrict__ vh, unsigned short* __restrict__ vt){
  __shared__ __align__(16) unsigned short t[64][72];
  int bh = blockIdx.x >> 5, st = blockIdx.x & 31;
  int s0 = st*64;
  int tid = threadIdx.x;
#pragma unroll
  for (int p = 0; p < 2; ++p){
    int u = tid + p*256;
    int row = u >> 3, ch = u & 7;
    *(us8*)&t[row][ch*8] = *(const us8*)(vh + ((size_t)bh*SEQ + s0 + row)*DH + ch*8);
  }
  __syncthreads();
#pragma unroll
  for (int p = 0; p < 2; ++p){
    int u = tid + p*256;
    int dr = u >> 3, ch = u & 7;
    us8 v;
#pragma unroll
    for (int j = 0; j < 8; ++j) v[j] = t[ch*8+j][dr];
    *(us8*)(vt + ((size_t)bh*DH + dr)*SEQ + s0 + ch*8) = v;
  }
}

// ---------------- fused attention core (double-buffered, 1 barrier per k-tile) -----
// R7 math; Kh/Vt double-buffered so commit(kt+1) never touches the buffer being
// read -> single __syncthreads per tile (31 vs R7's 62). Mask read from global
// (L1-hot 8KB row) to fit LDS 77.1 KB -> 2 blocks/CU.
__launch_bounds__(256, 2)
__global__ void k_attn(const unsigned short* __restrict__ qh, const unsigned short* __restrict__ kh,
                       const unsigned short* __restrict__ vt, const unsigned short* __restrict__ embk,
                       const float* __restrict__ mask,
                       unsigned short* __restrict__ Pb, float* __restrict__ Zout,
                       float* __restrict__ ctxu){
  __shared__ unsigned short qrl[64*NREL];                          // 32.9 KB
  __shared__ __align__(16) unsigned short Kh[2][64][72], Vt[2][64][72], Pl[64][72];

  const int tid = threadIdx.x, w = tid >> 6, lane = tid & 63;
  const int bh = blockIdx.x >> 5, qt = blockIdx.x & 31;
  const int b = bh >> 4;
  const int q0 = qt * 64;
  const int fr = lane & 15, fo = (lane >> 4) * 8, fq = (lane >> 4) * 4;
  const float* mrow = mask + (size_t)b*SEQ;

  // Q fragments direct from global (rows = this wave's 16 q rows)
  bf16x8 q_hi[2];
  {
    size_t base = ((size_t)bh*SEQ + q0 + w*16 + fr) * DH;
#pragma unroll
    for (int ks = 0; ks < 2; ++ks)
      q_hi[ks] = *(const bf16x8*)(qh + base + ks*32 + fo);
  }

  // qrel[q][r] = qh[q] . rel_k_emb[r] via MFMA (wave-private rows)
#pragma unroll 1
  for (int jt = 0; jt < 17; ++jt){
    f32x4 a = {};
#pragma unroll
    for (int ks = 0; ks < 2; ++ks){
      bf16x8 e = *(const bf16x8*)(embk + ((size_t)(jt*16 + fr))*DH + ks*32 + fo);
      a = __builtin_amdgcn_mfma_f32_16x16x32_bf16(q_hi[ks], e, a, 0,0,0);
    }
    int rr = jt*16 + fr;
#pragma unroll
    for (int r = 0; r < 4; ++r){
      if (rr < NREL) qrl[(w*16 + fq + r)*NREL + rr] = f2bf(a[r]);
    }
  }
  // clamped-tail rel constants (pre-scaled), wave-private read
  float rcL[4], rcR[4];
#pragma unroll
  for (int r = 0; r < 4; ++r){
    int ql = w*16 + fq + r;
    rcL[r] = b2f(qrl[ql*NREL + 0])   * 0.125f;
    rcR[r] = b2f(qrl[ql*NREL + 256]) * 0.125f;
  }

  const unsigned short* kb = kh + (size_t)bh*SEQ*DH;
  const unsigned short* vb = vt + (size_t)bh*DH*SEQ;

  const int srow = tid >> 3, sch = (tid & 7) * 8;          // staging: thread -> (row, chunk)
  us8 rKh[2], rVt[2];
  auto issue = [&](int kt){
#pragma unroll
    for (int p = 0; p < 2; ++p){
      int row = srow + p*32;
      rKh[p] = *(const us8*)(kb + ((size_t)(kt*64 + row))*DH + sch);
      rVt[p] = *(const us8*)(vb + ((size_t)row)*SEQ + kt*64 + sch);
    }
  };
  auto commit = [&](int buf){
#pragma unroll
    for (int p = 0; p < 2; ++p){
      int row = srow + p*32;
      *(us8*)&Kh[buf][row][sch] = rKh[p];
      *(us8*)&Vt[buf][row][sch] = rVt[p];
    }
  };

  float zpart[4] = {0.f,0.f,0.f,0.f};
  f32x4 ctx[4] = {};

  issue(0); commit(0);
  __syncthreads();                       // tile 0 visible

#pragma unroll 1
  for (int kt = 0; kt < 32; ++kt){
    const int pb = kt & 1;
    if (kt < 31) issue(kt + 1);          // T14: loads in flight during compute

    const bool leftU  = (kt*64 + 191) <= q0;   // all kg-qg <= -128
    const bool rightU = (kt*64) >= (q0 + 191); // all kg-qg >= +128

    float pv[4][4];
#pragma unroll
    for (int c = 0; c < 4; ++c){
      f32x4 a = {};
#pragma unroll
      for (int ks = 0; ks < 2; ++ks){
        bf16x8 kf = *(const bf16x8*)&Kh[pb][c*16 + fr][ks*32 + fo];
        a = __builtin_amdgcn_mfma_f32_16x16x32_bf16(q_hi[ks], kf, a, 0,0,0);
      }
      int kg = kt*64 + c*16 + fr;
      float mv = mrow[kg] * (-1e9f);
      if (leftU){
#pragma unroll
        for (int r = 0; r < 4; ++r)
          pv[c][r] = __expf(a[r]*0.125f + rcL[r] + mv);
      } else if (rightU){
#pragma unroll
        for (int r = 0; r < 4; ++r)
          pv[c][r] = __expf(a[r]*0.125f + rcR[r] + mv);
      } else {
#pragma unroll
        for (int r = 0; r < 4; ++r){
          int ql = w*16 + fq + r;
          int qg = q0 + ql;
          int dd = kg - qg; dd = min(max(dd, -128), 128);
          float rel = b2f(qrl[ql*NREL + dd + 128]);
          pv[c][r] = __expf((a[r] + rel)*0.125f + mv);
        }
      }
    }
    // deferred Z partials
#pragma unroll
    for (int r = 0; r < 4; ++r)
      zpart[r] += pv[0][r] + pv[1][r] + pv[2][r] + pv[3][r];
    // P tile to LDS (bf16, wave-private rows) for PV redistribution + global dump
#pragma unroll
    for (int c = 0; c < 4; ++c)
#pragma unroll
      for (int r = 0; r < 4; ++r)
        Pl[w*16 + fq + r][c*16 + fr] = f2bf(pv[c][r]);
    {
      int lr = lane >> 2, ch = lane & 3;
      const unsigned short* src = &Pl[w*16 + lr][0];
      size_t gbase = ((size_t)bh*SEQ + q0 + w*16 + lr)*SEQ + kt*64;
      *(us8*)(Pb + gbase + ch*8)     = *(const us8*)(src + ch*8);
      *(us8*)(Pb + gbase + (ch+4)*8) = *(const us8*)(src + (ch+4)*8);
    }
    // PV: ctx += P @ V
#pragma unroll
    for (int ks = 0; ks < 2; ++ks){
      bf16x8 pf = *(const bf16x8*)&Pl[w*16 + fr][ks*32 + fo];
#pragma unroll
      for (int j = 0; j < 4; ++j){
        bf16x8 vf = *(const bf16x8*)&Vt[pb][j*16 + fr][ks*32 + fo];
        ctx[j] = __builtin_amdgcn_mfma_f32_16x16x32_bf16(pf, vf, ctx[j], 0,0,0);
      }
    }
    if (kt < 31){
      commit(pb ^ 1);                    // write kt+1 into the other buffer:
                                         // no wave reads it since the barrier
                                         // that ended iter kt-1
      __syncthreads();                   // tile kt+1 visible (single barrier/tile)
    }
  }

  // final Z reduce across the 16-lane k-groups
#pragma unroll
  for (int r = 0; r < 4; ++r){
    float part = zpart[r];
    part += __shfl_xor(part, 1);
    part += __shfl_xor(part, 2);
    part += __shfl_xor(part, 4);
    part += __shfl_xor(part, 8);
    zpart[r] = part;
  }
  if (fr == 0){
#pragma unroll
    for (int r = 0; r < 4; ++r)
      Zout[(size_t)bh*SEQ + q0 + w*16 + fq + r] = zpart[r];
  }
#pragma unroll
  for (int j = 0; j < 4; ++j)
#pragma unroll
    for (int r = 0; r < 4; ++r)
      ctxu[((size_t)bh*SEQ + q0 + w*16 + fq + r)*DH + j*16 + fr] = ctx[j][r];
}

// ---------------- normalize + rel-V (MFMA band matmul) + head merge ----------------
__launch_bounds__(256, 4)
__global__ void k_norm(const unsigned short* __restrict__ Pb, float* __restrict__ attn,
                       const float* __restrict__ Z,
                       const float* __restrict__ ctxu, const unsigned short* __restrict__ embT,
                       const float* __restrict__ rv, unsigned short* __restrict__ ctxb){
  __shared__ __align__(16) unsigned short band[64*256];   // 32 KB, XOR-swizzled rows
  __shared__ float invr[64], Lr[64], Rr[64];
  const int tid = threadIdx.x, w = tid >> 6, lane = tid & 63;
  const int bh = blockIdx.x >> 5, qt = blockIdx.x & 31;
  const int q0 = qt * 64;
  const int fr = lane & 15, fo = (lane >> 4) * 8, fq = (lane >> 4) * 4;

  {
    us8 z = {0,0,0,0,0,0,0,0};
    for (int i = tid; i < 64*256/8; i += 256) ((us8*)band)[i] = z;
  }
  __syncthreads();

  // Phase 1: each wave owns rows w*16 .. w*16+15
#pragma unroll 1
  for (int rr = 0; rr < 16; ++rr){
    int rl = w*16 + rr;
    int q = q0 + rl;
    size_t R = (size_t)bh*SEQ + q;
    float inv = 1.0f / Z[R];
    float la = 0.f, ra = 0.f;
    const us8* prow = (const us8*)(Pb + R*SEQ);
    float4* orow = (float4*)(attn + R*SEQ);
    unsigned short* brow = band + rl*256;
    const int sw = (rl & 7) << 3;
#pragma unroll 1
    for (int c = 0; c < 4; ++c){
      us8 p8 = prow[c*64 + lane];              // 8 bf16 elements
      float pe[8];
#pragma unroll
      for (int e = 0; e < 8; ++e) pe[e] = b2f(p8[e]);
      float4 o0 = {pe[0]*inv, pe[1]*inv, pe[2]*inv, pe[3]*inv};
      float4 o1 = {pe[4]*inv, pe[5]*inv, pe[6]*inv, pe[7]*inv};
      orow[(c*64 + lane)*2]     = o0;
      orow[(c*64 + lane)*2 + 1] = o1;
      int jlo = c*512 - q + 127;               // j of chunk's first column (uniform)
      if (jlo + 511 < 0){
        la += pe[0]+pe[1]+pe[2]+pe[3]+pe[4]+pe[5]+pe[6]+pe[7];
      } else if (jlo > 254){
        ra += pe[0]+pe[1]+pe[2]+pe[3]+pe[4]+pe[5]+pe[6]+pe[7];
      } else {
        int jb = jlo + lane*8;
#pragma unroll
        for (int e = 0; e < 8; ++e){
          int j = jb + e;
          if (j < 0)        la += pe[e];
          else if (j > 254) ra += pe[e];
          else              brow[j ^ sw] = p8[e];   // raw bf16 bits
        }
      }
    }
#pragma unroll
    for (int m = 1; m < 64; m <<= 1){
      la += __shfl_xor(la, m);
      ra += __shfl_xor(ra, m);
    }
    if (lane == 0){ invr[rl] = inv; Lr[rl] = la; Rr[rl] = ra; }
  }
  __syncthreads();

  // Phase 2: out_rel(unnorm)[64 rows][64 d] = band @ embT^T (embT from global, L2-hot)
  f32x4 acc[4] = {};
  {
    const int arow = w*16 + fr;
    const int asw = (arow & 7) << 3;
    const unsigned short* bandr = band + arow*256;
#pragma unroll
    for (int kk = 0; kk < 8; ++kk){
      bf16x8 af = *(const bf16x8*)&bandr[(kk*32 + fo) ^ asw];
#pragma unroll
      for (int jt = 0; jt < 4; ++jt){
        bf16x8 bfr = *(const bf16x8*)(embT + (size_t)(jt*16 + fr)*256 + kk*32 + fo);
        acc[jt] = __builtin_amdgcn_mfma_f32_16x16x32_bf16(af, bfr, acc[jt], 0,0,0);
      }
    }
  }

  // Epilogue: inv*(ctxu + band_matmul + tails), head-merge store
  const int b = bh >> 4, h = bh & 15;
#pragma unroll
  for (int jt = 0; jt < 4; ++jt){
    int d = jt*16 + fr;
    float e0 = rv[d], e256 = rv[(size_t)256*DH + d];
#pragma unroll
    for (int r = 0; r < 4; ++r){
      int rl = w*16 + fq + r;
      int q = q0 + rl;
      float cv = (ctxu[((size_t)bh*SEQ + q)*DH + d] + acc[jt][r] + Lr[rl]*e0 + Rr[rl]*e256) * invr[rl];
      ctxb[((size_t)b*SEQ + q)*DM + h*DH + d] = f2bf(cv);
    }
  }
}

// ---------------- output projection (plain bf16) ----------------
__launch_bounds__(256, 2)
__global__ void k_out(const unsigned short* __restrict__ A, const unsigned short* __restrict__ Bt,
                      const float* __restrict__ bias, float* __restrict__ out){
  __shared__ __align__(16) unsigned short sm[2*4096];
  const int tid = threadIdx.x;
  const int w = tid >> 6, lane = tid & 63;
  const int m0 = (blockIdx.x >> 3) * 128;
  const int n0 = (blockIdx.x & 7) * 128;
  const int wr = (w >> 1) * 64, wc = (w & 1) * 64;
  const int fr = lane & 15, fo = (lane >> 4)*8, fq = (lane >> 4)*4;
  f32x4 acc[4][4] = {};
  for (int k0 = 0; k0 < DM; k0 += 32){
    const unsigned short* srcs[2] = { A + (size_t)m0*DM + k0, Bt + (size_t)n0*DM + k0 };
#pragma unroll
    for (int t = 0; t < 2; ++t)
#pragma unroll
      for (int p = 0; p < 2; ++p){
        int o = p*4096 + tid*16;
        int row = o >> 6, cb = o & 63;
        const char* g = (const char*)(srcs[t] + (size_t)row*DM) + cb;
        char* l = ((char*)sm) + t*8192 + o;
        gload_lds16(g, l);
      }
    __syncthreads();
    bf16x8 af[4], bf[4];
#pragma unroll
    for (int i = 0; i < 4; ++i){
      af[i] = *(const bf16x8*)&sm[0*4096 + (wr + i*16 + fr)*32 + fo];
      bf[i] = *(const bf16x8*)&sm[1*4096 + (wc + i*16 + fr)*32 + fo];
    }
#pragma unroll
    for (int i = 0; i < 4; ++i)
#pragma unroll
      for (int j = 0; j < 4; ++j)
        acc[i][j] = __builtin_amdgcn_mfma_f32_16x16x32_bf16(af[i], bf[j], acc[i][j], 0,0,0);
    __syncthreads();
  }
#pragma unroll
  for (int i = 0; i < 4; ++i)
#pragma unroll
    for (int j = 0; j < 4; ++j){
      int col = n0 + wc + j*16 + fr;
      float bs = bias[col];
#pragma unroll
      for (int r = 0; r < 4; ++r){
        int row = m0 + wr + i*16 + fq + r;
        out[(size_t)row*DM + col] = acc[i][j][r] + bs;
      }
    }
}

// ---------------- host launch ----------------
extern "C" void kernel_launch(void* const* d_in, const int* in_sizes, int n_in,
                              void* d_out, int out_size, void* d_ws, size_t ws_size,
                              hipStream_t stream){
  const float* q    = (const float*)d_in[0];
  const float* k    = (const float*)d_in[1];
  const float* v    = (const float*)d_in[2];
  const float* mask = (const float*)d_in[3];
  const float* wq   = (const float*)d_in[4];
  const float* bq   = (const float*)d_in[5];
  const float* wk   = (const float*)d_in[6];
  const float* bk   = (const float*)d_in[7];
  const float* wv   = (const float*)d_in[8];
  const float* bv   = (const float*)d_in[9];
  const float* wo   = (const float*)d_in[10];
  const float* bo   = (const float*)d_in[11];
  const float* rk   = (const float*)d_in[12];
  const float* rv   = (const float*)d_in[13];

  float* out  = (float*)d_out;
  float* attn = out + (size_t)ROWS*DM;     // tuple output: [out | attn]

  char* p = (char*)d_ws;
  size_t used = 0;
  auto alloc = [&](size_t bytes) -> char* {
    char* r = p;
    size_t a = (bytes + 255) & ~(size_t)255;
    p += a; used += a;
    return r;
  };
  const size_t NE  = (size_t)ROWS*DM;      // 4096*1024
  unsigned short* qb   = (unsigned short*)alloc(NE*2);             // q bf16
  unsigned short* kbf  = (unsigned short*)alloc(NE*2);             // k bf16
  unsigned short* vbf  = (unsigned short*)alloc(NE*2);             // v bf16
  unsigned short* wqt  = (unsigned short*)alloc((size_t)DM*DM*2);
  unsigned short* wkt  = (unsigned short*)alloc((size_t)DM*DM*2);
  unsigned short* wvt  = (unsigned short*)alloc((size_t)DM*DM*2);
  unsigned short* wot  = (unsigned short*)alloc((size_t)DM*DM*2);
  unsigned short* qh   = (unsigned short*)alloc(NE*2);
  unsigned short* kh   = (unsigned short*)alloc(NE*2);
  unsigned short* vh   = (unsigned short*)alloc(NE*2);
  unsigned short* vht  = (unsigned short*)alloc(NE*2);
  unsigned short* embk = (unsigned short*)alloc((size_t)272*64*2);
  unsigned short* embT = (unsigned short*)alloc((size_t)64*256*2);
  float* Zb   = (float*)alloc((size_t)BHN*SEQ*4);
  float* ctxu = (float*)alloc((size_t)BHN*SEQ*DH*4);
  unsigned short* ctxb = (unsigned short*)alloc(NE*2);
  unsigned short* Pb   = (unsigned short*)alloc((size_t)BHN*SEQ*SEQ*2);  // 268 MB bf16
  if (used > ws_size) return;   // insufficient workspace -> fail visibly

  const int N4 = (int)(NE/4);
  k_cast<<<2048, 256, 0, stream>>>(q, qb, N4);
  k_cast<<<2048, 256, 0, stream>>>(k, kbf, N4);
  k_cast<<<2048, 256, 0, stream>>>(v, vbf, N4);
  dim3 tg(16,16);
  k_wtrans<<<tg, 256, 0, stream>>>(wq, wqt);
  k_wtrans<<<tg, 256, 0, stream>>>(wk, wkt);
  k_wtrans<<<tg, 256, 0, stream>>>(wv, wvt);
  k_wtrans<<<tg, 256, 0, stream>>>(wo, wot);
  k_embk<<<(272*64+255)/256, 256, 0, stream>>>(rk, embk);
  k_embt<<<64, 256, 0, stream>>>(rv, embT);

  k_proj<<<256, 256, 0, stream>>>(qb,  wqt, bq, qh);
  k_proj<<<256, 256, 0, stream>>>(kbf, wkt, bk, kh);
  k_proj<<<256, 256, 0, stream>>>(vbf, wvt, bv, vh);
  k_vtrans<<<1024, 256, 0, stream>>>(vh, vht);

  k_attn<<<1024, 256, 0, stream>>>(qh, kh, vht, embk, mask, Pb, Zb, ctxu);
  k_norm<<<1024, 256, 0, stream>>>(Pb, attn, Zb, ctxu, embT, rv, ctxb);
  k_out<<<256, 256, 0, stream>>>(ctxb, wot, bo, out);
}

// Round 12
// 541.527 us; speedup vs baseline: 1.0566x; 1.0566x over previous
//
#include <hip/hip_runtime.h>
#include <hip/hip_bf16.h>
#include <cstdint>
#include <cstddef>

// Problem constants (fixed by reference)
#define DM   1024
#define NH   16
#define DH   64
#define SEQ  2048
#define BB   2
#define NREL 257
#define BHN  (BB*NH)          // 32 (b,h) pairs
#define ROWS (BB*SEQ)         // 4096 (b,s) rows

typedef __attribute__((ext_vector_type(8))) short bf16x8;
typedef __attribute__((ext_vector_type(4))) float f32x4;
typedef __attribute__((ext_vector_type(8))) unsigned short us8;
typedef __attribute__((ext_vector_type(4))) unsigned short us4;

__device__ __forceinline__ unsigned short f2bf(float x){
  union { float f; unsigned u; } v; v.f = x;
  unsigned r = v.u + 0x7fffu + ((v.u >> 16) & 1u);
  return (unsigned short)(r >> 16);
}
__device__ __forceinline__ float b2f(unsigned short h){
  union { unsigned u; float f; } v; v.u = ((unsigned)h) << 16;
  return v.f;
}

__device__ __forceinline__ void gload_lds16(const void* g, void* l){
  __builtin_amdgcn_global_load_lds((const __attribute__((address_space(1))) unsigned int*)g,
                                   (__attribute__((address_space(3))) unsigned int*)l, 16, 0, 0);
}

// ---------------- prep kernels ----------------

// fp32 -> bf16 cast (vectorized), n multiple of 4
__global__ void k_cast(const float* __restrict__ x, unsigned short* __restrict__ o, int n4){
  int i = blockIdx.x*blockDim.x + threadIdx.x;
  int st = gridDim.x*blockDim.x;
  for (; i < n4; i += st){
    float4 f = ((const float4*)x)[i];
    us4 v = { f2bf(f.x), f2bf(f.y), f2bf(f.z), f2bf(f.w) };
    *(us4*)(o + (size_t)i*4) = v;
  }
}

// W[1024][1024] fp32 -> T[1024][1024] bf16 with T[n][k] = W[k][n]
__global__ void k_wtrans(const float* __restrict__ W, unsigned short* __restrict__ T){
  __shared__ float t[64][65];
  int k0 = blockIdx.x*64, n0 = blockIdx.y*64;
  int tid = threadIdx.x;
  for (int u = tid; u < 4096; u += 256){
    int r = u >> 6, c = u & 63;
    t[r][c] = W[(size_t)(k0+r)*DM + n0 + c];
  }
  __syncthreads();
  for (int u = tid; u < 4096; u += 256){
    int r = u >> 6, c = u & 63;   // output row n0+r, col k0+c
    T[(size_t)(n0+r)*DM + k0 + c] = f2bf(t[c][r]);
  }
}

// rel_k_emb [257][64] fp32 -> [272][64] bf16 (zero pad rows 257..271); clamped load
__global__ void k_embk(const float* __restrict__ e, unsigned short* __restrict__ eb){
  int i = blockIdx.x*256 + threadIdx.x;
  if (i >= 272*64) return;
  int r = i >> 6;
  float v = e[min(i, NREL*64 - 1)];
  eb[i] = (r < NREL) ? f2bf(v) : (unsigned short)0;
}

// rel_v_emb -> embT[d][j] = rv[j+1][d] bf16, j in [0,255), col 255 zero-padded
__global__ void k_embt(const float* __restrict__ rv, unsigned short* __restrict__ embT){
  int i = blockIdx.x*256 + threadIdx.x;
  if (i >= 64*256) return;
  int d = i >> 8, j = i & 255;
  float v = rv[(size_t)min(j+1, 256)*DH + d];
  embT[i] = (j < 255) ? f2bf(v) : (unsigned short)0;
}

// ---------------- projection GEMM (plain bf16, head-scatter epilogue) ----------------
__launch_bounds__(256, 2)
__global__ void k_proj(const unsigned short* __restrict__ A, const unsigned short* __restrict__ Bt,
                       const float* __restrict__ bias, unsigned short* __restrict__ O){
  __shared__ __align__(16) unsigned short sm[2*4096];
  const int tid = threadIdx.x;
  const int w = tid >> 6, lane = tid & 63;
  const int m0 = (blockIdx.x >> 3) * 128;
  const int n0 = (blockIdx.x & 7) * 128;
  const int wr = (w >> 1) * 64, wc = (w & 1) * 64;
  const int fr = lane & 15, fo = (lane >> 4)*8, fq = (lane >> 4)*4;
  f32x4 acc[4][4] = {};
  for (int k0 = 0; k0 < DM; k0 += 32){
    const unsigned short* srcs[2] = { A + (size_t)m0*DM + k0, Bt + (size_t)n0*DM + k0 };
#pragma unroll
    for (int t = 0; t < 2; ++t)
#pragma unroll
      for (int p = 0; p < 2; ++p){
        int o = p*4096 + tid*16;
        int row = o >> 6, cb = o & 63;
        const char* g = (const char*)(srcs[t] + (size_t)row*DM) + cb;
        char* l = ((char*)sm) + t*8192 + o;
        gload_lds16(g, l);
      }
    __syncthreads();
    bf16x8 af[4], bf[4];
#pragma unroll
    for (int i = 0; i < 4; ++i){
      af[i] = *(const bf16x8*)&sm[0*4096 + (wr + i*16 + fr)*32 + fo];
      bf[i] = *(const bf16x8*)&sm[1*4096 + (wc + i*16 + fr)*32 + fo];
    }
#pragma unroll
    for (int i = 0; i < 4; ++i)
#pragma unroll
      for (int j = 0; j < 4; ++j)
        acc[i][j] = __builtin_amdgcn_mfma_f32_16x16x32_bf16(af[i], bf[j], acc[i][j], 0,0,0);
    __syncthreads();
  }
#pragma unroll
  for (int i = 0; i < 4; ++i)
#pragma unroll
    for (int j = 0; j < 4; ++j){
      int col = n0 + wc + j*16 + fr;
      float bs = bias[col];
      int h = col >> 6, d = col & 63;
#pragma unroll
      for (int r = 0; r < 4; ++r){
        int row = m0 + wr + i*16 + fq + r;
        int b = row >> 11, s = row & 2047;
        O[((size_t)(b*NH + h)*SEQ + s)*DH + d] = f2bf(acc[i][j][r] + bs);
      }
    }
}

// ---------------- V transpose: vh[bh][s][d] -> vht[bh][d][s] ----------------
__global__ void k_vtrans(const unsigned short* __restrict__ vh, unsigned short* __restrict__ vt){
  __shared__ __align__(16) unsigned short t[64][72];
  int bh = blockIdx.x >> 5, st = blockIdx.x & 31;
  int s0 = st*64;
  int tid = threadIdx.x;
#pragma unroll
  for (int p = 0; p < 2; ++p){
    int u = tid + p*256;
    int row = u >> 3, ch = u & 7;
    *(us8*)&t[row][ch*8] = *(const us8*)(vh + ((size_t)bh*SEQ + s0 + row)*DH + ch*8);
  }
  __syncthreads();
#pragma unroll
  for (int p = 0; p < 2; ++p){
    int u = tid + p*256;
    int dr = u >> 3, ch = u & 7;
    us8 v;
#pragma unroll
    for (int j = 0; j < 8; ++j) v[j] = t[ch*8+j][dr];
    *(us8*)(vt + ((size_t)bh*DH + dr)*SEQ + s0 + ch*8) = v;
  }
}

// ---------------- fused attention core (dbuf, 1 barrier/tile, mask reg-prefetch) ---
// R11 structure; mask values for tile kt prefetched into registers during tile
// kt-1 (alongside K/V issue) so the exp path consumes pure registers.
__launch_bounds__(256, 2)
__global__ void k_attn(const unsigned short* __restrict__ qh, const unsigned short* __restrict__ kh,
                       const unsigned short* __restrict__ vt, const unsigned short* __restrict__ embk,
                       const float* __restrict__ mask,
                       unsigned short* __restrict__ Pb, float* __restrict__ Zout,
                       float* __restrict__ ctxu){
  __shared__ unsigned short qrl[64*NREL];                          // 32.9 KB
  __shared__ __align__(16) unsigned short Kh[2][64][72], Vt[2][64][72], Pl[64][72];

  const int tid = threadIdx.x, w = tid >> 6, lane = tid & 63;
  const int bh = blockIdx.x >> 5, qt = blockIdx.x & 31;
  const int b = bh >> 4;
  const int q0 = qt * 64;
  const int fr = lane & 15, fo = (lane >> 4) * 8, fq = (lane >> 4) * 4;
  const float* mrow = mask + (size_t)b*SEQ;

  // Q fragments direct from global (rows = this wave's 16 q rows)
  bf16x8 q_hi[2];
  {
    size_t base = ((size_t)bh*SEQ + q0 + w*16 + fr) * DH;
#pragma unroll
    for (int ks = 0; ks < 2; ++ks)
      q_hi[ks] = *(const bf16x8*)(qh + base + ks*32 + fo);
  }

  // qrel[q][r] = qh[q] . rel_k_emb[r] via MFMA (wave-private rows)
#pragma unroll 1
  for (int jt = 0; jt < 17; ++jt){
    f32x4 a = {};
#pragma unroll
    for (int ks = 0; ks < 2; ++ks){
      bf16x8 e = *(const bf16x8*)(embk + ((size_t)(jt*16 + fr))*DH + ks*32 + fo);
      a = __builtin_amdgcn_mfma_f32_16x16x32_bf16(q_hi[ks], e, a, 0,0,0);
    }
    int rr = jt*16 + fr;
#pragma unroll
    for (int r = 0; r < 4; ++r){
      if (rr < NREL) qrl[(w*16 + fq + r)*NREL + rr] = f2bf(a[r]);
    }
  }
  // clamped-tail rel constants (pre-scaled), wave-private read
  float rcL[4], rcR[4];
#pragma unroll
  for (int r = 0; r < 4; ++r){
    int ql = w*16 + fq + r;
    rcL[r] = b2f(qrl[ql*NREL + 0])   * 0.125f;
    rcR[r] = b2f(qrl[ql*NREL + 256]) * 0.125f;
  }

  const unsigned short* kb = kh + (size_t)bh*SEQ*DH;
  const unsigned short* vb = vt + (size_t)bh*DH*SEQ;

  const int srow = tid >> 3, sch = (tid & 7) * 8;          // staging: thread -> (row, chunk)
  us8 rKh[2], rVt[2];
  auto issue = [&](int kt){
#pragma unroll
    for (int p = 0; p < 2; ++p){
      int row = srow + p*32;
      rKh[p] = *(const us8*)(kb + ((size_t)(kt*64 + row))*DH + sch);
      rVt[p] = *(const us8*)(vb + ((size_t)row)*SEQ + kt*64 + sch);
    }
  };
  auto commit = [&](int buf){
#pragma unroll
    for (int p = 0; p < 2; ++p){
      int row = srow + p*32;
      *(us8*)&Kh[buf][row][sch] = rKh[p];
      *(us8*)&Vt[buf][row][sch] = rVt[p];
    }
  };

  float zpart[4] = {0.f,0.f,0.f,0.f};
  f32x4 ctx[4] = {};

  // mask prefetch pipeline: mv4 = tile kt's premultiplied mask (registers)
  float mv4[4];
#pragma unroll
  for (int c = 0; c < 4; ++c) mv4[c] = mrow[c*16 + fr] * (-1e9f);

  issue(0); commit(0);
  __syncthreads();                       // tile 0 visible

#pragma unroll 1
  for (int kt = 0; kt < 32; ++kt){
    const int pb = kt & 1;
    float mvn[4];
    if (kt < 31){
      issue(kt + 1);                     // T14: K/V loads in flight during compute
#pragma unroll
      for (int c = 0; c < 4; ++c)        // mask for kt+1 in flight too
        mvn[c] = mrow[(kt+1)*64 + c*16 + fr] * (-1e9f);
    }

    const bool leftU  = (kt*64 + 191) <= q0;   // all kg-qg <= -128
    const bool rightU = (kt*64) >= (q0 + 191); // all kg-qg >= +128

    float pv[4][4];
#pragma unroll
    for (int c = 0; c < 4; ++c){
      f32x4 a = {};
#pragma unroll
      for (int ks = 0; ks < 2; ++ks){
        bf16x8 kf = *(const bf16x8*)&Kh[pb][c*16 + fr][ks*32 + fo];
        a = __builtin_amdgcn_mfma_f32_16x16x32_bf16(q_hi[ks], kf, a, 0,0,0);
      }
      int kg = kt*64 + c*16 + fr;
      float mv = mv4[c];
      if (leftU){
#pragma unroll
        for (int r = 0; r < 4; ++r)
          pv[c][r] = __expf(a[r]*0.125f + rcL[r] + mv);
      } else if (rightU){
#pragma unroll
        for (int r = 0; r < 4; ++r)
          pv[c][r] = __expf(a[r]*0.125f + rcR[r] + mv);
      } else {
#pragma unroll
        for (int r = 0; r < 4; ++r){
          int ql = w*16 + fq + r;
          int qg = q0 + ql;
          int dd = kg - qg; dd = min(max(dd, -128), 128);
          float rel = b2f(qrl[ql*NREL + dd + 128]);
          pv[c][r] = __expf((a[r] + rel)*0.125f + mv);
        }
      }
    }
    // deferred Z partials
#pragma unroll
    for (int r = 0; r < 4; ++r)
      zpart[r] += pv[0][r] + pv[1][r] + pv[2][r] + pv[3][r];
    // P tile to LDS (bf16, wave-private rows) for PV redistribution + global dump
#pragma unroll
    for (int c = 0; c < 4; ++c)
#pragma unroll
      for (int r = 0; r < 4; ++r)
        Pl[w*16 + fq + r][c*16 + fr] = f2bf(pv[c][r]);
    {
      int lr = lane >> 2, ch = lane & 3;
      const unsigned short* src = &Pl[w*16 + lr][0];
      size_t gbase = ((size_t)bh*SEQ + q0 + w*16 + lr)*SEQ + kt*64;
      *(us8*)(Pb + gbase + ch*8)     = *(const us8*)(src + ch*8);
      *(us8*)(Pb + gbase + (ch+4)*8) = *(const us8*)(src + (ch+4)*8);
    }
    // PV: ctx += P @ V
#pragma unroll
    for (int ks = 0; ks < 2; ++ks){
      bf16x8 pf = *(const bf16x8*)&Pl[w*16 + fr][ks*32 + fo];
#pragma unroll
      for (int j = 0; j < 4; ++j){
        bf16x8 vf = *(const bf16x8*)&Vt[pb][j*16 + fr][ks*32 + fo];
        ctx[j] = __builtin_amdgcn_mfma_f32_16x16x32_bf16(pf, vf, ctx[j], 0,0,0);
      }
    }
    if (kt < 31){
      commit(pb ^ 1);                    // write kt+1 into the other buffer
      __syncthreads();                   // tile kt+1 visible (single barrier/tile)
#pragma unroll
      for (int c = 0; c < 4; ++c) mv4[c] = mvn[c];
    }
  }

  // final Z reduce across the 16-lane k-groups
#pragma unroll
  for (int r = 0; r < 4; ++r){
    float part = zpart[r];
    part += __shfl_xor(part, 1);
    part += __shfl_xor(part, 2);
    part += __shfl_xor(part, 4);
    part += __shfl_xor(part, 8);
    zpart[r] = part;
  }
  if (fr == 0){
#pragma unroll
    for (int r = 0; r < 4; ++r)
      Zout[(size_t)bh*SEQ + q0 + w*16 + fq + r] = zpart[r];
  }
#pragma unroll
  for (int j = 0; j < 4; ++j)
#pragma unroll
    for (int r = 0; r < 4; ++r)
      ctxu[((size_t)bh*SEQ + q0 + w*16 + fq + r)*DH + j*16 + fr] = ctx[j][r];
}

// ---------------- normalize + rel-V (MFMA band matmul) + head merge ----------------
__launch_bounds__(256, 4)
__global__ void k_norm(const unsigned short* __restrict__ Pb, float* __restrict__ attn,
                       const float* __restrict__ Z,
                       const float* __restrict__ ctxu, const unsigned short* __restrict__ embT,
                       const float* __restrict__ rv, unsigned short* __restrict__ ctxb){
  __shared__ __align__(16) unsigned short band[64*256];   // 32 KB, XOR-swizzled rows
  __shared__ float invr[64], Lr[64], Rr[64];
  const int tid = threadIdx.x, w = tid >> 6, lane = tid & 63;
  const int bh = blockIdx.x >> 5, qt = blockIdx.x & 31;
  const int q0 = qt * 64;
  const int fr = lane & 15, fo = (lane >> 4) * 8, fq = (lane >> 4) * 4;

  {
    us8 z = {0,0,0,0,0,0,0,0};
    for (int i = tid; i < 64*256/8; i += 256) ((us8*)band)[i] = z;
  }
  __syncthreads();

  // Phase 1: each wave owns rows w*16 .. w*16+15
#pragma unroll 1
  for (int rr = 0; rr < 16; ++rr){
    int rl = w*16 + rr;
    int q = q0 + rl;
    size_t R = (size_t)bh*SEQ + q;
    float inv = 1.0f / Z[R];
    float la = 0.f, ra = 0.f;
    const us8* prow = (const us8*)(Pb + R*SEQ);
    float4* orow = (float4*)(attn + R*SEQ);
    unsigned short* brow = band + rl*256;
    const int sw = (rl & 7) << 3;
#pragma unroll 1
    for (int c = 0; c < 4; ++c){
      us8 p8 = prow[c*64 + lane];              // 8 bf16 elements
      float pe[8];
#pragma unroll
      for (int e = 0; e < 8; ++e) pe[e] = b2f(p8[e]);
      float4 o0 = {pe[0]*inv, pe[1]*inv, pe[2]*inv, pe[3]*inv};
      float4 o1 = {pe[4]*inv, pe[5]*inv, pe[6]*inv, pe[7]*inv};
      orow[(c*64 + lane)*2]     = o0;
      orow[(c*64 + lane)*2 + 1] = o1;
      int jlo = c*512 - q + 127;               // j of chunk's first column (uniform)
      if (jlo + 511 < 0){
        la += pe[0]+pe[1]+pe[2]+pe[3]+pe[4]+pe[5]+pe[6]+pe[7];
      } else if (jlo > 254){
        ra += pe[0]+pe[1]+pe[2]+pe[3]+pe[4]+pe[5]+pe[6]+pe[7];
      } else {
        int jb = jlo + lane*8;
#pragma unroll
        for (int e = 0; e < 8; ++e){
          int j = jb + e;
          if (j < 0)        la += pe[e];
          else if (j > 254) ra += pe[e];
          else              brow[j ^ sw] = p8[e];   // raw bf16 bits
        }
      }
    }
#pragma unroll
    for (int m = 1; m < 64; m <<= 1){
      la += __shfl_xor(la, m);
      ra += __shfl_xor(ra, m);
    }
    if (lane == 0){ invr[rl] = inv; Lr[rl] = la; Rr[rl] = ra; }
  }
  __syncthreads();

  // Phase 2: out_rel(unnorm)[64 rows][64 d] = band @ embT^T (embT from global, L2-hot)
  f32x4 acc[4] = {};
  {
    const int arow = w*16 + fr;
    const int asw = (arow & 7) << 3;
    const unsigned short* bandr = band + arow*256;
#pragma unroll
    for (int kk = 0; kk < 8; ++kk){
      bf16x8 af = *(const bf16x8*)&bandr[(kk*32 + fo) ^ asw];
#pragma unroll
      for (int jt = 0; jt < 4; ++jt){
        bf16x8 bfr = *(const bf16x8*)(embT + (size_t)(jt*16 + fr)*256 + kk*32 + fo);
        acc[jt] = __builtin_amdgcn_mfma_f32_16x16x32_bf16(af, bfr, acc[jt], 0,0,0);
      }
    }
  }

  // Epilogue: inv*(ctxu + band_matmul + tails), head-merge store
  const int b = bh >> 4, h = bh & 15;
#pragma unroll
  for (int jt = 0; jt < 4; ++jt){
    int d = jt*16 + fr;
    float e0 = rv[d], e256 = rv[(size_t)256*DH + d];
#pragma unroll
    for (int r = 0; r < 4; ++r){
      int rl = w*16 + fq + r;
      int q = q0 + rl;
      float cv = (ctxu[((size_t)bh*SEQ + q)*DH + d] + acc[jt][r] + Lr[rl]*e0 + Rr[rl]*e256) * invr[rl];
      ctxb[((size_t)b*SEQ + q)*DM + h*DH + d] = f2bf(cv);
    }
  }
}

// ---------------- output projection (plain bf16) ----------------
__launch_bounds__(256, 2)
__global__ void k_out(const unsigned short* __restrict__ A, const unsigned short* __restrict__ Bt,
                      const float* __restrict__ bias, float* __restrict__ out){
  __shared__ __align__(16) unsigned short sm[2*4096];
  const int tid = threadIdx.x;
  const int w = tid >> 6, lane = tid & 63;
  const int m0 = (blockIdx.x >> 3) * 128;
  const int n0 = (blockIdx.x & 7) * 128;
  const int wr = (w >> 1) * 64, wc = (w & 1) * 64;
  const int fr = lane & 15, fo = (lane >> 4)*8, fq = (lane >> 4)*4;
  f32x4 acc[4][4] = {};
  for (int k0 = 0; k0 < DM; k0 += 32){
    const unsigned short* srcs[2] = { A + (size_t)m0*DM + k0, Bt + (size_t)n0*DM + k0 };
#pragma unroll
    for (int t = 0; t < 2; ++t)
#pragma unroll
      for (int p = 0; p < 2; ++p){
        int o = p*4096 + tid*16;
        int row = o >> 6, cb = o & 63;
        const char* g = (const char*)(srcs[t] + (size_t)row*DM) + cb;
        char* l = ((char*)sm) + t*8192 + o;
        gload_lds16(g, l);
      }
    __syncthreads();
    bf16x8 af[4], bf[4];
#pragma unroll
    for (int i = 0; i < 4; ++i){
      af[i] = *(const bf16x8*)&sm[0*4096 + (wr + i*16 + fr)*32 + fo];
      bf[i] = *(const bf16x8*)&sm[1*4096 + (wc + i*16 + fr)*32 + fo];
    }
#pragma unroll
    for (int i = 0; i < 4; ++i)
#pragma unroll
      for (int j = 0; j < 4; ++j)
        acc[i][j] = __builtin_amdgcn_mfma_f32_16x16x32_bf16(af[i], bf[j], acc[i][j], 0,0,0);
    __syncthreads();
  }
#pragma unroll
  for (int i = 0; i < 4; ++i)
#pragma unroll
    for (int j = 0; j < 4; ++j){
      int col = n0 + wc + j*16 + fr;
      float bs = bias[col];
#pragma unroll
      for (int r = 0; r < 4; ++r){
        int row = m0 + wr + i*16 + fq + r;
        out[(size_t)row*DM + col] = acc[i][j][r] + bs;
      }
    }
}

// ---------------- host launch ----------------
extern "C" void kernel_launch(void* const* d_in, const int* in_sizes, int n_in,
                              void* d_out, int out_size, void* d_ws, size_t ws_size,
                              hipStream_t stream){
  const float* q    = (const float*)d_in[0];
  const float* k    = (const float*)d_in[1];
  const float* v    = (const float*)d_in[2];
  const float* mask = (const float*)d_in[3];
  const float* wq   = (const float*)d_in[4];
  const float* bq   = (const float*)d_in[5];
  const float* wk   = (const float*)d_in[6];
  const float* bk   = (const float*)d_in[7];
  const float* wv   = (const float*)d_in[8];
  const float* bv   = (const float*)d_in[9];
  const float* wo   = (const float*)d_in[10];
  const float* bo   = (const float*)d_in[11];
  const float* rk   = (const float*)d_in[12];
  const float* rv   = (const float*)d_in[13];

  float* out  = (float*)d_out;
  float* attn = out + (size_t)ROWS*DM;     // tuple output: [out | attn]

  char* p = (char*)d_ws;
  size_t used = 0;
  auto alloc = [&](size_t bytes) -> char* {
    char* r = p;
    size_t a = (bytes + 255) & ~(size_t)255;
    p += a; used += a;
    return r;
  };
  const size_t NE  = (size_t)ROWS*DM;      // 4096*1024
  unsigned short* qb   = (unsigned short*)alloc(NE*2);             // q bf16
  unsigned short* kbf  = (unsigned short*)alloc(NE*2);             // k bf16
  unsigned short* vbf  = (unsigned short*)alloc(NE*2);             // v bf16
  unsigned short* wqt  = (unsigned short*)alloc((size_t)DM*DM*2);
  unsigned short* wkt  = (unsigned short*)alloc((size_t)DM*DM*2);
  unsigned short* wvt  = (unsigned short*)alloc((size_t)DM*DM*2);
  unsigned short* wot  = (unsigned short*)alloc((size_t)DM*DM*2);
  unsigned short* qh   = (unsigned short*)alloc(NE*2);
  unsigned short* kh   = (unsigned short*)alloc(NE*2);
  unsigned short* vh   = (unsigned short*)alloc(NE*2);
  unsigned short* vht  = (unsigned short*)alloc(NE*2);
  unsigned short* embk = (unsigned short*)alloc((size_t)272*64*2);
  unsigned short* embT = (unsigned short*)alloc((size_t)64*256*2);
  float* Zb   = (float*)alloc((size_t)BHN*SEQ*4);
  float* ctxu = (float*)alloc((size_t)BHN*SEQ*DH*4);
  unsigned short* ctxb = (unsigned short*)alloc(NE*2);
  unsigned short* Pb   = (unsigned short*)alloc((size_t)BHN*SEQ*SEQ*2);  // 268 MB bf16
  if (used > ws_size) return;   // insufficient workspace -> fail visibly

  const int N4 = (int)(NE/4);
  k_cast<<<2048, 256, 0, stream>>>(q, qb, N4);
  k_cast<<<2048, 256, 0, stream>>>(k, kbf, N4);
  k_cast<<<2048, 256, 0, stream>>>(v, vbf, N4);
  dim3 tg(16,16);
  k_wtrans<<<tg, 256, 0, stream>>>(wq, wqt);
  k_wtrans<<<tg, 256, 0, stream>>>(wk, wkt);
  k_wtrans<<<tg, 256, 0, stream>>>(wv, wvt);
  k_wtrans<<<tg, 256, 0, stream>>>(wo, wot);
  k_embk<<<(272*64+255)/256, 256, 0, stream>>>(rk, embk);
  k_embt<<<64, 256, 0, stream>>>(rv, embT);

  k_proj<<<256, 256, 0, stream>>>(qb,  wqt, bq, qh);
  k_proj<<<256, 256, 0, stream>>>(kbf, wkt, bk, kh);
  k_proj<<<256, 256, 0, stream>>>(vbf, wvt, bv, vh);
  k_vtrans<<<1024, 256, 0, stream>>>(vh, vht);

  k_attn<<<1024, 256, 0, stream>>>(qh, kh, vht, embk, mask, Pb, Zb, ctxu);
  k_norm<<<1024, 256, 0, stream>>>(Pb, attn, Zb, ctxu, embT, rv, ctxb);
  k_out<<<256, 256, 0, stream>>>(ctxb, wot, bo, out);
}

// Round 13
// 510.652 us; speedup vs baseline: 1.1204x; 1.0605x over previous
//
#include <hip/hip_runtime.h>
#include <hip/hip_bf16.h>
#include <cstdint>
#include <cstddef>

// Problem constants (fixed by reference)
#define DM   1024
#define NH   16
#define DH   64
#define SEQ  2048
#define BB   2
#define NREL 257
#define BHN  (BB*NH)          // 32 (b,h) pairs
#define ROWS (BB*SEQ)         // 4096 (b,s) rows

typedef __attribute__((ext_vector_type(8))) short bf16x8;
typedef __attribute__((ext_vector_type(4))) float f32x4;
typedef __attribute__((ext_vector_type(8))) unsigned short us8;
typedef __attribute__((ext_vector_type(4))) unsigned short us4;

__device__ __forceinline__ unsigned short f2bf(float x){
  union { float f; unsigned u; } v; v.f = x;
  unsigned r = v.u + 0x7fffu + ((v.u >> 16) & 1u);
  return (unsigned short)(r >> 16);
}
__device__ __forceinline__ float b2f(unsigned short h){
  union { unsigned u; float f; } v; v.u = ((unsigned)h) << 16;
  return v.f;
}

__device__ __forceinline__ void gload_lds16(const void* g, void* l){
  __builtin_amdgcn_global_load_lds((const __attribute__((address_space(1))) unsigned int*)g,
                                   (__attribute__((address_space(3))) unsigned int*)l, 16, 0, 0);
}

// ---------------- prep kernels ----------------

// fp32 -> bf16 cast (vectorized), n multiple of 4
__global__ void k_cast(const float* __restrict__ x, unsigned short* __restrict__ o, int n4){
  int i = blockIdx.x*blockDim.x + threadIdx.x;
  int st = gridDim.x*blockDim.x;
  for (; i < n4; i += st){
    float4 f = ((const float4*)x)[i];
    us4 v = { f2bf(f.x), f2bf(f.y), f2bf(f.z), f2bf(f.w) };
    *(us4*)(o + (size_t)i*4) = v;
  }
}

// W[1024][1024] fp32 -> T[1024][1024] bf16 with T[n][k] = W[k][n]
__global__ void k_wtrans(const float* __restrict__ W, unsigned short* __restrict__ T){
  __shared__ float t[64][65];
  int k0 = blockIdx.x*64, n0 = blockIdx.y*64;
  int tid = threadIdx.x;
  for (int u = tid; u < 4096; u += 256){
    int r = u >> 6, c = u & 63;
    t[r][c] = W[(size_t)(k0+r)*DM + n0 + c];
  }
  __syncthreads();
  for (int u = tid; u < 4096; u += 256){
    int r = u >> 6, c = u & 63;   // output row n0+r, col k0+c
    T[(size_t)(n0+r)*DM + k0 + c] = f2bf(t[c][r]);
  }
}

// rel_k_emb [257][64] fp32 -> [272][64] bf16 (zero pad rows 257..271); clamped load
__global__ void k_embk(const float* __restrict__ e, unsigned short* __restrict__ eb){
  int i = blockIdx.x*256 + threadIdx.x;
  if (i >= 272*64) return;
  int r = i >> 6;
  float v = e[min(i, NREL*64 - 1)];
  eb[i] = (r < NREL) ? f2bf(v) : (unsigned short)0;
}

// rel_v_emb -> embT[d][j] = rv[j+1][d] bf16, j in [0,255), col 255 zero-padded
__global__ void k_embt(const float* __restrict__ rv, unsigned short* __restrict__ embT){
  int i = blockIdx.x*256 + threadIdx.x;
  if (i >= 64*256) return;
  int d = i >> 8, j = i & 255;
  float v = rv[(size_t)min(j+1, 256)*DH + d];
  embT[i] = (j < 255) ? f2bf(v) : (unsigned short)0;
}

// ---------------- projection GEMM (plain bf16, head-scatter epilogue) ----------------
__launch_bounds__(256, 2)
__global__ void k_proj(const unsigned short* __restrict__ A, const unsigned short* __restrict__ Bt,
                       const float* __restrict__ bias, unsigned short* __restrict__ O){
  __shared__ __align__(16) unsigned short sm[2*4096];
  const int tid = threadIdx.x;
  const int w = tid >> 6, lane = tid & 63;
  const int m0 = (blockIdx.x >> 3) * 128;
  const int n0 = (blockIdx.x & 7) * 128;
  const int wr = (w >> 1) * 64, wc = (w & 1) * 64;
  const int fr = lane & 15, fo = (lane >> 4)*8, fq = (lane >> 4)*4;
  f32x4 acc[4][4] = {};
  for (int k0 = 0; k0 < DM; k0 += 32){
    const unsigned short* srcs[2] = { A + (size_t)m0*DM + k0, Bt + (size_t)n0*DM + k0 };
#pragma unroll
    for (int t = 0; t < 2; ++t)
#pragma unroll
      for (int p = 0; p < 2; ++p){
        int o = p*4096 + tid*16;
        int row = o >> 6, cb = o & 63;
        const char* g = (const char*)(srcs[t] + (size_t)row*DM) + cb;
        char* l = ((char*)sm) + t*8192 + o;
        gload_lds16(g, l);
      }
    __syncthreads();
    bf16x8 af[4], bf[4];
#pragma unroll
    for (int i = 0; i < 4; ++i){
      af[i] = *(const bf16x8*)&sm[0*4096 + (wr + i*16 + fr)*32 + fo];
      bf[i] = *(const bf16x8*)&sm[1*4096 + (wc + i*16 + fr)*32 + fo];
    }
#pragma unroll
    for (int i = 0; i < 4; ++i)
#pragma unroll
      for (int j = 0; j < 4; ++j)
        acc[i][j] = __builtin_amdgcn_mfma_f32_16x16x32_bf16(af[i], bf[j], acc[i][j], 0,0,0);
    __syncthreads();
  }
#pragma unroll
  for (int i = 0; i < 4; ++i)
#pragma unroll
    for (int j = 0; j < 4; ++j){
      int col = n0 + wc + j*16 + fr;
      float bs = bias[col];
      int h = col >> 6, d = col & 63;
#pragma unroll
      for (int r = 0; r < 4; ++r){
        int row = m0 + wr + i*16 + fq + r;
        int b = row >> 11, s = row & 2047;
        O[((size_t)(b*NH + h)*SEQ + s)*DH + d] = f2bf(acc[i][j][r] + bs);
      }
    }
}

// ---------------- V transpose: vh[bh][s][d] -> vht[bh][d][s] ----------------
__global__ void k_vtrans(const unsigned short* __restrict__ vh, unsigned short* __restrict__ vt){
  __shared__ __align__(16) unsigned short t[64][72];
  int bh = blockIdx.x >> 5, st = blockIdx.x & 31;
  int s0 = st*64;
  int tid = threadIdx.x;
#pragma unroll
  for (int p = 0; p < 2; ++p){
    int u = tid + p*256;
    int row = u >> 3, ch = u & 7;
    *(us8*)&t[row][ch*8] = *(const us8*)(vh + ((size_t)bh*SEQ + s0 + row)*DH + ch*8);
  }
  __syncthreads();
#pragma unroll
  for (int p = 0; p < 2; ++p){
    int u = tid + p*256;
    int dr = u >> 3, ch = u & 7;
    us8 v;
#pragma unroll
    for (int j = 0; j < 8; ++j) v[j] = t[ch*8+j][dr];
    *(us8*)(vt + ((size_t)bh*DH + dr)*SEQ + s0 + ch*8) = v;
  }
}

// ---------------- fused attention core (staged + T14 prefetch + uniform fast path) --
// Plain bf16 QK^T. Per kt: issue next tile's loads early (regs), compute current
// from LDS, barrier, commit regs->LDS, barrier.  (Proven R7 configuration.)
__launch_bounds__(256, 2)
__global__ void k_attn(const unsigned short* __restrict__ qh, const unsigned short* __restrict__ kh,
                       const unsigned short* __restrict__ vt, const unsigned short* __restrict__ embk,
                       const float* __restrict__ mask,
                       unsigned short* __restrict__ Pb, float* __restrict__ Zout,
                       float* __restrict__ ctxu){
  __shared__ unsigned short qrl[64*NREL];                  // qrel bf16, row stride 257
  __shared__ __align__(16) unsigned short Kh[64][72], Vt[64][72], Pl[64][72];
  __shared__ float mls[SEQ];                               // premultiplied mask row

  const int tid = threadIdx.x, w = tid >> 6, lane = tid & 63;
  const int bh = blockIdx.x >> 5, qt = blockIdx.x & 31;
  const int b = bh >> 4;
  const int q0 = qt * 64;
  const int fr = lane & 15, fo = (lane >> 4) * 8, fq = (lane >> 4) * 4;

  // mask row -> LDS premultiplied
  for (int i = tid; i < SEQ; i += 256) mls[i] = mask[b*SEQ + i] * (-1e9f);

  // Q fragments direct from global (rows = this wave's 16 q rows)
  bf16x8 q_hi[2];
  {
    size_t base = ((size_t)bh*SEQ + q0 + w*16 + fr) * DH;
#pragma unroll
    for (int ks = 0; ks < 2; ++ks)
      q_hi[ks] = *(const bf16x8*)(qh + base + ks*32 + fo);
  }

  // qrel[q][r] = qh[q] . rel_k_emb[r] via MFMA (wave-private rows)
#pragma unroll 1
  for (int jt = 0; jt < 17; ++jt){
    f32x4 a = {};
#pragma unroll
    for (int ks = 0; ks < 2; ++ks){
      bf16x8 e = *(const bf16x8*)(embk + ((size_t)(jt*16 + fr))*DH + ks*32 + fo);
      a = __builtin_amdgcn_mfma_f32_16x16x32_bf16(q_hi[ks], e, a, 0,0,0);
    }
    int rr = jt*16 + fr;
#pragma unroll
    for (int r = 0; r < 4; ++r){
      if (rr < NREL) qrl[(w*16 + fq + r)*NREL + rr] = f2bf(a[r]);
    }
  }
  // clamped-tail rel constants (pre-scaled), wave-private read
  float rcL[4], rcR[4];
#pragma unroll
  for (int r = 0; r < 4; ++r){
    int ql = w*16 + fq + r;
    rcL[r] = b2f(qrl[ql*NREL + 0])   * 0.125f;
    rcR[r] = b2f(qrl[ql*NREL + 256]) * 0.125f;
  }

  const unsigned short* kb = kh + (size_t)bh*SEQ*DH;
  const unsigned short* vb = vt + (size_t)bh*DH*SEQ;

  const int srow = tid >> 3, sch = (tid & 7) * 8;          // staging: thread -> (row, chunk)
  us8 rKh[2], rVt[2];
  auto issue = [&](int kt){
#pragma unroll
    for (int p = 0; p < 2; ++p){
      int row = srow + p*32;
      rKh[p] = *(const us8*)(kb + ((size_t)(kt*64 + row))*DH + sch);
      rVt[p] = *(const us8*)(vb + ((size_t)row)*SEQ + kt*64 + sch);
    }
  };
  auto commit = [&](){
#pragma unroll
    for (int p = 0; p < 2; ++p){
      int row = srow + p*32;
      *(us8*)&Kh[row][sch] = rKh[p];
      *(us8*)&Vt[row][sch] = rVt[p];
    }
  };

  float zpart[4] = {0.f,0.f,0.f,0.f};
  f32x4 ctx[4] = {};

  issue(0); commit();
  __syncthreads();                       // tile 0 + mls visible

#pragma unroll 1
  for (int kt = 0; kt < 32; ++kt){
    if (kt < 31) issue(kt + 1);          // T14: loads in flight during compute

    const bool leftU  = (kt*64 + 191) <= q0;   // all kg-qg <= -128
    const bool rightU = (kt*64) >= (q0 + 191); // all kg-qg >= +128

    float pv[4][4];
#pragma unroll
    for (int c = 0; c < 4; ++c){
      f32x4 a = {};
#pragma unroll
      for (int ks = 0; ks < 2; ++ks){
        bf16x8 kf = *(const bf16x8*)&Kh[c*16 + fr][ks*32 + fo];
        a = __builtin_amdgcn_mfma_f32_16x16x32_bf16(q_hi[ks], kf, a, 0,0,0);
      }
      int kg = kt*64 + c*16 + fr;
      float mv = mls[kg];
      if (leftU){
#pragma unroll
        for (int r = 0; r < 4; ++r)
          pv[c][r] = __expf(a[r]*0.125f + rcL[r] + mv);
      } else if (rightU){
#pragma unroll
        for (int r = 0; r < 4; ++r)
          pv[c][r] = __expf(a[r]*0.125f + rcR[r] + mv);
      } else {
#pragma unroll
        for (int r = 0; r < 4; ++r){
          int ql = w*16 + fq + r;
          int qg = q0 + ql;
          int dd = kg - qg; dd = min(max(dd, -128), 128);
          float rel = b2f(qrl[ql*NREL + dd + 128]);
          pv[c][r] = __expf((a[r] + rel)*0.125f + mv);
        }
      }
    }
    // deferred Z partials
#pragma unroll
    for (int r = 0; r < 4; ++r)
      zpart[r] += pv[0][r] + pv[1][r] + pv[2][r] + pv[3][r];
    // P tile to LDS (bf16) for PV redistribution + coalesced global dump
#pragma unroll
    for (int c = 0; c < 4; ++c)
#pragma unroll
      for (int r = 0; r < 4; ++r)
        Pl[w*16 + fq + r][c*16 + fr] = f2bf(pv[c][r]);
    {
      int lr = lane >> 2, ch = lane & 3;
      const unsigned short* src = &Pl[w*16 + lr][0];
      size_t gbase = ((size_t)bh*SEQ + q0 + w*16 + lr)*SEQ + kt*64;
      *(us8*)(Pb + gbase + ch*8)     = *(const us8*)(src + ch*8);
      *(us8*)(Pb + gbase + (ch+4)*8) = *(const us8*)(src + (ch+4)*8);
    }
    // PV: ctx += P @ V
#pragma unroll
    for (int ks = 0; ks < 2; ++ks){
      bf16x8 pf = *(const bf16x8*)&Pl[w*16 + fr][ks*32 + fo];
#pragma unroll
      for (int j = 0; j < 4; ++j){
        bf16x8 vf = *(const bf16x8*)&Vt[j*16 + fr][ks*32 + fo];
        ctx[j] = __builtin_amdgcn_mfma_f32_16x16x32_bf16(pf, vf, ctx[j], 0,0,0);
      }
    }
    if (kt < 31){
      __syncthreads();                   // everyone done reading tile kt
      commit();                          // write kt+1
      __syncthreads();                   // tile kt+1 visible
    }
  }

  // final Z reduce across the 16-lane k-groups
#pragma unroll
  for (int r = 0; r < 4; ++r){
    float part = zpart[r];
    part += __shfl_xor(part, 1);
    part += __shfl_xor(part, 2);
    part += __shfl_xor(part, 4);
    part += __shfl_xor(part, 8);
    zpart[r] = part;
  }
  if (fr == 0){
#pragma unroll
    for (int r = 0; r < 4; ++r)
      Zout[(size_t)bh*SEQ + q0 + w*16 + fq + r] = zpart[r];
  }
#pragma unroll
  for (int j = 0; j < 4; ++j)
#pragma unroll
    for (int r = 0; r < 4; ++r)
      ctxu[((size_t)bh*SEQ + q0 + w*16 + fq + r)*DH + j*16 + fr] = ctx[j][r];
}

// ---------------- normalize + rel-V (MFMA band matmul) + head merge ----------------
__launch_bounds__(256, 4)
__global__ void k_norm(const unsigned short* __restrict__ Pb, float* __restrict__ attn,
                       const float* __restrict__ Z,
                       const float* __restrict__ ctxu, const unsigned short* __restrict__ embT,
                       const float* __restrict__ rv, unsigned short* __restrict__ ctxb){
  __shared__ __align__(16) unsigned short band[64*256];   // 32 KB, XOR-swizzled rows
  __shared__ float invr[64], Lr[64], Rr[64];
  const int tid = threadIdx.x, w = tid >> 6, lane = tid & 63;
  const int bh = blockIdx.x >> 5, qt = blockIdx.x & 31;
  const int q0 = qt * 64;
  const int fr = lane & 15, fo = (lane >> 4) * 8, fq = (lane >> 4) * 4;

  {
    us8 z = {0,0,0,0,0,0,0,0};
    for (int i = tid; i < 64*256/8; i += 256) ((us8*)band)[i] = z;
  }
  __syncthreads();

  // Phase 1: each wave owns rows w*16 .. w*16+15
#pragma unroll 1
  for (int rr = 0; rr < 16; ++rr){
    int rl = w*16 + rr;
    int q = q0 + rl;
    size_t R = (size_t)bh*SEQ + q;
    float inv = 1.0f / Z[R];
    float la = 0.f, ra = 0.f;
    const us8* prow = (const us8*)(Pb + R*SEQ);
    float4* orow = (float4*)(attn + R*SEQ);
    unsigned short* brow = band + rl*256;
    const int sw = (rl & 7) << 3;
#pragma unroll 1
    for (int c = 0; c < 4; ++c){
      us8 p8 = prow[c*64 + lane];              // 8 bf16 elements
      float pe[8];
#pragma unroll
      for (int e = 0; e < 8; ++e) pe[e] = b2f(p8[e]);
      float4 o0 = {pe[0]*inv, pe[1]*inv, pe[2]*inv, pe[3]*inv};
      float4 o1 = {pe[4]*inv, pe[5]*inv, pe[6]*inv, pe[7]*inv};
      orow[(c*64 + lane)*2]     = o0;
      orow[(c*64 + lane)*2 + 1] = o1;
      int jlo = c*512 - q + 127;               // j of chunk's first column (uniform)
      if (jlo + 511 < 0){
        la += pe[0]+pe[1]+pe[2]+pe[3]+pe[4]+pe[5]+pe[6]+pe[7];
      } else if (jlo > 254){
        ra += pe[0]+pe[1]+pe[2]+pe[3]+pe[4]+pe[5]+pe[6]+pe[7];
      } else {
        int jb = jlo + lane*8;
#pragma unroll
        for (int e = 0; e < 8; ++e){
          int j = jb + e;
          if (j < 0)        la += pe[e];
          else if (j > 254) ra += pe[e];
          else              brow[j ^ sw] = p8[e];   // raw bf16 bits
        }
      }
    }
#pragma unroll
    for (int m = 1; m < 64; m <<= 1){
      la += __shfl_xor(la, m);
      ra += __shfl_xor(ra, m);
    }
    if (lane == 0){ invr[rl] = inv; Lr[rl] = la; Rr[rl] = ra; }
  }
  __syncthreads();

  // Phase 2: out_rel(unnorm)[64 rows][64 d] = band @ embT^T (embT from global, L2-hot)
  f32x4 acc[4] = {};
  {
    const int arow = w*16 + fr;
    const int asw = (arow & 7) << 3;
    const unsigned short* bandr = band + arow*256;
#pragma unroll
    for (int kk = 0; kk < 8; ++kk){
      bf16x8 af = *(const bf16x8*)&bandr[(kk*32 + fo) ^ asw];
#pragma unroll
      for (int jt = 0; jt < 4; ++jt){
        bf16x8 bfr = *(const bf16x8*)(embT + (size_t)(jt*16 + fr)*256 + kk*32 + fo);
        acc[jt] = __builtin_amdgcn_mfma_f32_16x16x32_bf16(af, bfr, acc[jt], 0,0,0);
      }
    }
  }

  // Epilogue: inv*(ctxu + band_matmul + tails), head-merge store
  const int b = bh >> 4, h = bh & 15;
#pragma unroll
  for (int jt = 0; jt < 4; ++jt){
    int d = jt*16 + fr;
    float e0 = rv[d], e256 = rv[(size_t)256*DH + d];
#pragma unroll
    for (int r = 0; r < 4; ++r){
      int rl = w*16 + fq + r;
      int q = q0 + rl;
      float cv = (ctxu[((size_t)bh*SEQ + q)*DH + d] + acc[jt][r] + Lr[rl]*e0 + Rr[rl]*e256) * invr[rl];
      ctxb[((size_t)b*SEQ + q)*DM + h*DH + d] = f2bf(cv);
    }
  }
}

// ---------------- output projection (plain bf16) ----------------
__launch_bounds__(256, 2)
__global__ void k_out(const unsigned short* __restrict__ A, const unsigned short* __restrict__ Bt,
                      const float* __restrict__ bias, float* __restrict__ out){
  __shared__ __align__(16) unsigned short sm[2*4096];
  const int tid = threadIdx.x;
  const int w = tid >> 6, lane = tid & 63;
  const int m0 = (blockIdx.x >> 3) * 128;
  const int n0 = (blockIdx.x & 7) * 128;
  const int wr = (w >> 1) * 64, wc = (w & 1) * 64;
  const int fr = lane & 15, fo = (lane >> 4)*8, fq = (lane >> 4)*4;
  f32x4 acc[4][4] = {};
  for (int k0 = 0; k0 < DM; k0 += 32){
    const unsigned short* srcs[2] = { A + (size_t)m0*DM + k0, Bt + (size_t)n0*DM + k0 };
#pragma unroll
    for (int t = 0; t < 2; ++t)
#pragma unroll
      for (int p = 0; p < 2; ++p){
        int o = p*4096 + tid*16;
        int row = o >> 6, cb = o & 63;
        const char* g = (const char*)(srcs[t] + (size_t)row*DM) + cb;
        char* l = ((char*)sm) + t*8192 + o;
        gload_lds16(g, l);
      }
    __syncthreads();
    bf16x8 af[4], bf[4];
#pragma unroll
    for (int i = 0; i < 4; ++i){
      af[i] = *(const bf16x8*)&sm[0*4096 + (wr + i*16 + fr)*32 + fo];
      bf[i] = *(const bf16x8*)&sm[1*4096 + (wc + i*16 + fr)*32 + fo];
    }
#pragma unroll
    for (int i = 0; i < 4; ++i)
#pragma unroll
      for (int j = 0; j < 4; ++j)
        acc[i][j] = __builtin_amdgcn_mfma_f32_16x16x32_bf16(af[i], bf[j], acc[i][j], 0,0,0);
    __syncthreads();
  }
#pragma unroll
  for (int i = 0; i < 4; ++i)
#pragma unroll
    for (int j = 0; j < 4; ++j){
      int col = n0 + wc + j*16 + fr;
      float bs = bias[col];
#pragma unroll
      for (int r = 0; r < 4; ++r){
        int row = m0 + wr + i*16 + fq + r;
        out[(size_t)row*DM + col] = acc[i][j][r] + bs;
      }
    }
}

// ---------------- host launch ----------------
extern "C" void kernel_launch(void* const* d_in, const int* in_sizes, int n_in,
                              void* d_out, int out_size, void* d_ws, size_t ws_size,
                              hipStream_t stream){
  const float* q    = (const float*)d_in[0];
  const float* k    = (const float*)d_in[1];
  const float* v    = (const float*)d_in[2];
  const float* mask = (const float*)d_in[3];
  const float* wq   = (const float*)d_in[4];
  const float* bq   = (const float*)d_in[5];
  const float* wk   = (const float*)d_in[6];
  const float* bk   = (const float*)d_in[7];
  const float* wv   = (const float*)d_in[8];
  const float* bv   = (const float*)d_in[9];
  const float* wo   = (const float*)d_in[10];
  const float* bo   = (const float*)d_in[11];
  const float* rk   = (const float*)d_in[12];
  const float* rv   = (const float*)d_in[13];

  float* out  = (float*)d_out;
  float* attn = out + (size_t)ROWS*DM;     // tuple output: [out | attn]

  char* p = (char*)d_ws;
  size_t used = 0;
  auto alloc = [&](size_t bytes) -> char* {
    char* r = p;
    size_t a = (bytes + 255) & ~(size_t)255;
    p += a; used += a;
    return r;
  };
  const size_t NE  = (size_t)ROWS*DM;      // 4096*1024
  unsigned short* qb   = (unsigned short*)alloc(NE*2);             // q bf16
  unsigned short* kbf  = (unsigned short*)alloc(NE*2);             // k bf16
  unsigned short* vbf  = (unsigned short*)alloc(NE*2);             // v bf16
  unsigned short* wqt  = (unsigned short*)alloc((size_t)DM*DM*2);
  unsigned short* wkt  = (unsigned short*)alloc((size_t)DM*DM*2);
  unsigned short* wvt  = (unsigned short*)alloc((size_t)DM*DM*2);
  unsigned short* wot  = (unsigned short*)alloc((size_t)DM*DM*2);
  unsigned short* qh   = (unsigned short*)alloc(NE*2);
  unsigned short* kh   = (unsigned short*)alloc(NE*2);
  unsigned short* vh   = (unsigned short*)alloc(NE*2);
  unsigned short* vht  = (unsigned short*)alloc(NE*2);
  unsigned short* embk = (unsigned short*)alloc((size_t)272*64*2);
  unsigned short* embT = (unsigned short*)alloc((size_t)64*256*2);
  float* Zb   = (float*)alloc((size_t)BHN*SEQ*4);
  float* ctxu = (float*)alloc((size_t)BHN*SEQ*DH*4);
  unsigned short* ctxb = (unsigned short*)alloc(NE*2);
  unsigned short* Pb   = (unsigned short*)alloc((size_t)BHN*SEQ*SEQ*2);  // 268 MB bf16
  if (used > ws_size) return;   // insufficient workspace -> fail visibly

  const int N4 = (int)(NE/4);
  k_cast<<<2048, 256, 0, stream>>>(q, qb, N4);
  k_cast<<<2048, 256, 0, stream>>>(k, kbf, N4);
  k_cast<<<2048, 256, 0, stream>>>(v, vbf, N4);
  dim3 tg(16,16);
  k_wtrans<<<tg, 256, 0, stream>>>(wq, wqt);
  k_wtrans<<<tg, 256, 0, stream>>>(wk, wkt);
  k_wtrans<<<tg, 256, 0, stream>>>(wv, wvt);
  k_wtrans<<<tg, 256, 0, stream>>>(wo, wot);
  k_embk<<<(272*64+255)/256, 256, 0, stream>>>(rk, embk);
  k_embt<<<64, 256, 0, stream>>>(rv, embT);

  k_proj<<<256, 256, 0, stream>>>(qb,  wqt, bq, qh);
  k_proj<<<256, 256, 0, stream>>>(kbf, wkt, bk, kh);
  k_proj<<<256, 256, 0, stream>>>(vbf, wvt, bv, vh);
  k_vtrans<<<1024, 256, 0, stream>>>(vh, vht);

  k_attn<<<1024, 256, 0, stream>>>(qh, kh, vht, embk, mask, Pb, Zb, ctxu);
  k_norm<<<1024, 256, 0, stream>>>(Pb, attn, Zb, ctxu, embT, rv, ctxb);
  k_out<<<256, 256, 0, stream>>>(ctxb, wot, bo, out);
}